// Round 9
// baseline (85.369 us; speedup 1.0000x reference)
//
#include <hip/hip_runtime.h>

// MMD loss: mean(delta @ delta.T) == ||colsum(source - target)||^2 / N^2.
// O(N*D) streaming reduction (67 MB read).
// Cost model (R2-R8 consistent): node OH ~4.2us each, colsum ~11us
// (~6.1 TB/s = at the float4-copy ceiling), finale ~2us. R8: cg grid.sync
// costs ~35us -> refuted. This version: ONE kernel, hand-rolled light
// completion protocol (1 spinning lane/block, s_sleep backoff):
//   block0 entry: counters=0, out=0, release flag=MAGIC
//   each block: R6 load engine -> slice store -> fence -> ticket=atomicAdd
//   last 64 finishers: spin counter==512, each folds 4 float4-columns
//   (32KB) -> atomicAdd(out); last finale block resets flag/counters -> 0
// so every replay (and the post-poison first replay) is deterministic.

#define MMD_N 8192
#define MMD_D 1024
#define CS_BLOCKS 512
#define CS_THREADS 512
#define TEAMS 2
#define ROWS_PER_TEAM 8   // CS_BLOCKS * TEAMS * ROWS_PER_TEAM == MMD_N
#define NFIN 64           // elected finale blocks
#define MAGIC 0x5F3759DFu
#define INV_N2 1.4901161193847656e-8f  // 1 / 8192^2

__device__ __forceinline__ unsigned ctl_load(unsigned* p) {
    return __hip_atomic_load(p, __ATOMIC_ACQUIRE, __HIP_MEMORY_SCOPE_AGENT);
}

__global__ __launch_bounds__(CS_THREADS, 4) void mmd_onepass(
    const float* __restrict__ src, const float* __restrict__ tgt,
    float* __restrict__ ws, float* __restrict__ out) {
    const int tid  = threadIdx.x;
    const int team = tid >> 8;    // 0..1
    const int col4 = tid & 255;   // float4 column
    const int bid  = blockIdx.x;
    unsigned* ctl = reinterpret_cast<unsigned*>(ws + CS_BLOCKS * MMD_D);
    // ctl[0]=ticket counter, ctl[1]=finale-done counter, ctl[2]=init flag

    if (bid == 0 && tid == 0) {
        ctl[0] = 0u;
        ctl[1] = 0u;
        out[0] = 0.f;
        __threadfence();
        __hip_atomic_store(&ctl[2], MAGIC, __ATOMIC_RELEASE, __HIP_MEMORY_SCOPE_AGENT);
    }

    // ---- phase 1: R6-proven load engine ----
    const int row0 = bid * (TEAMS * ROWS_PER_TEAM) + team * ROWS_PER_TEAM;
    const float4* s4 = reinterpret_cast<const float4*>(src);
    const float4* t4 = reinterpret_cast<const float4*>(tgt);

    float4 s[ROWS_PER_TEAM], t[ROWS_PER_TEAM];
#pragma unroll
    for (int r = 0; r < ROWS_PER_TEAM; ++r)
        s[r] = s4[(row0 + r) * (MMD_D / 4) + col4];
#pragma unroll
    for (int r = 0; r < ROWS_PER_TEAM; ++r)
        t[r] = t4[(row0 + r) * (MMD_D / 4) + col4];

    float4 acc = make_float4(0.f, 0.f, 0.f, 0.f);
#pragma unroll
    for (int r = 0; r < ROWS_PER_TEAM; ++r) {
        acc.x += s[r].x - t[r].x;
        acc.y += s[r].y - t[r].y;
        acc.z += s[r].z - t[r].z;
        acc.w += s[r].w - t[r].w;
    }

    __shared__ float4 red[TEAMS][256];
    red[team][col4] = acc;
    __syncthreads();
    if (tid < 256) {
        float4 a = red[0][tid];
        float4 b = red[1][tid];
        float4 tot;
        tot.x = a.x + b.x; tot.y = a.y + b.y;
        tot.z = a.z + b.z; tot.w = a.w + b.w;
        reinterpret_cast<float4*>(ws)[bid * 256 + tid] = tot;
    }

    // ---- ticket: elect the last NFIN finishers as finale blocks ----
    __shared__ int s_rank;
    if (tid == 0) {
        __threadfence();  // release our slice store
        // ensure counters were zeroed by block 0 (flag set at its entry,
        // ~11us before any block reaches here)
        while (ctl_load(&ctl[2]) != MAGIC) __builtin_amdgcn_s_sleep(8);
        s_rank = (int)__hip_atomic_fetch_add(&ctl[0], 1u, __ATOMIC_ACQ_REL,
                                             __HIP_MEMORY_SCOPE_AGENT);
    }
    __syncthreads();
    const int rank = s_rank;                 // block-uniform
    if (rank < CS_BLOCKS - NFIN) return;     // whole block exits

    // ---- finale: block r of NFIN folds 4 float4-columns over 512 slices ----
    if (tid == 0) {
        while (ctl_load(&ctl[0]) != CS_BLOCKS) __builtin_amdgcn_s_sleep(16);
    }
    __syncthreads();
    __threadfence();  // acquire all slice stores

    const int r   = rank - (CS_BLOCKS - NFIN);     // 0..63
    const int col = r * 4 + (tid >> 7);            // float4 column, 128 thr each
    const int sl0 = tid & 127;
    const float4* w4 = reinterpret_cast<const float4*>(ws);

    float4 a2 = make_float4(0.f, 0.f, 0.f, 0.f);
#pragma unroll
    for (int k = 0; k < CS_BLOCKS / 128; ++k) {    // 4 slices per thread
        float4 v = w4[(sl0 + 128 * k) * 256 + col];
        a2.x += v.x; a2.y += v.y; a2.z += v.z; a2.w += v.w;
    }
    // reduce over the 128 threads (2 waves) of this column
    for (int off = 32; off > 0; off >>= 1) {
        a2.x += __shfl_down(a2.x, off, 64);
        a2.y += __shfl_down(a2.y, off, 64);
        a2.z += __shfl_down(a2.z, off, 64);
        a2.w += __shfl_down(a2.w, off, 64);
    }
    __shared__ float4 wred[8];   // one entry per wave
    if ((tid & 63) == 0) wred[tid >> 6] = a2;
    __syncthreads();
    if ((tid & 127) == 0) {
        float4 a = wred[tid >> 6];
        float4 b = wred[(tid >> 6) + 1];
        float4 tot;
        tot.x = a.x + b.x; tot.y = a.y + b.y;
        tot.z = a.z + b.z; tot.w = a.w + b.w;
        float sq = tot.x * tot.x + tot.y * tot.y + tot.z * tot.z + tot.w * tot.w;
        atomicAdd(out, sq * INV_N2);
    }

    // ---- last finale block resets control words for the next call ----
    if (tid == 0) {
        __threadfence();
        unsigned d = __hip_atomic_fetch_add(&ctl[1], 1u, __ATOMIC_ACQ_REL,
                                            __HIP_MEMORY_SCOPE_AGENT);
        if (d == NFIN - 1) {
            __hip_atomic_store(&ctl[2], 0u, __ATOMIC_RELEASE, __HIP_MEMORY_SCOPE_AGENT);
            __threadfence();
            ctl[0] = 0u;
            ctl[1] = 0u;
            __threadfence();
        }
    }
}

// ---------------- fallback: proven R6 2-kernel path ----------------
__global__ __launch_bounds__(CS_THREADS) void mmd_colsum_fb(
    const float* __restrict__ src, const float* __restrict__ tgt,
    float* __restrict__ ws, float* __restrict__ out) {
    const int tid  = threadIdx.x;
    const int team = tid >> 8;
    const int col4 = tid & 255;
    const int row0 = blockIdx.x * (TEAMS * ROWS_PER_TEAM) + team * ROWS_PER_TEAM;
    const float4* s4 = reinterpret_cast<const float4*>(src);
    const float4* t4 = reinterpret_cast<const float4*>(tgt);

    if (blockIdx.x == 0 && tid == 0) out[0] = 0.f;

    float4 s[ROWS_PER_TEAM], t[ROWS_PER_TEAM];
#pragma unroll
    for (int r = 0; r < ROWS_PER_TEAM; ++r)
        s[r] = s4[(row0 + r) * (MMD_D / 4) + col4];
#pragma unroll
    for (int r = 0; r < ROWS_PER_TEAM; ++r)
        t[r] = t4[(row0 + r) * (MMD_D / 4) + col4];

    float4 acc = make_float4(0.f, 0.f, 0.f, 0.f);
#pragma unroll
    for (int r = 0; r < ROWS_PER_TEAM; ++r) {
        acc.x += s[r].x - t[r].x;
        acc.y += s[r].y - t[r].y;
        acc.z += s[r].z - t[r].z;
        acc.w += s[r].w - t[r].w;
    }

    __shared__ float4 red[TEAMS][256];
    red[team][col4] = acc;
    __syncthreads();
    if (tid < 256) {
        float4 a = red[0][tid];
        float4 b = red[1][tid];
        float4 tot;
        tot.x = a.x + b.x; tot.y = a.y + b.y;
        tot.z = a.z + b.z; tot.w = a.w + b.w;
        reinterpret_cast<float4*>(ws)[blockIdx.x * 256 + tid] = tot;
    }
}

__global__ __launch_bounds__(256) void mmd_finale_fb(
    const float* __restrict__ ws, float* __restrict__ out) {
    const int tid  = threadIdx.x;
    const int j    = tid >> 6;
    const int lane = tid & 63;
    const int c    = blockIdx.x * 4 + j;
    const float4* w4 = reinterpret_cast<const float4*>(ws);

    float4 acc = make_float4(0.f, 0.f, 0.f, 0.f);
#pragma unroll
    for (int k = 0; k < CS_BLOCKS / 64; ++k) {
        float4 v = w4[(lane + 64 * k) * 256 + c];
        acc.x += v.x; acc.y += v.y; acc.z += v.z; acc.w += v.w;
    }
    for (int off = 32; off > 0; off >>= 1) {
        acc.x += __shfl_down(acc.x, off, 64);
        acc.y += __shfl_down(acc.y, off, 64);
        acc.z += __shfl_down(acc.z, off, 64);
        acc.w += __shfl_down(acc.w, off, 64);
    }
    if (lane == 0) {
        float sq = acc.x * acc.x + acc.y * acc.y + acc.z * acc.z + acc.w * acc.w;
        atomicAdd(out, sq * INV_N2);
    }
}

extern "C" void kernel_launch(void* const* d_in, const int* in_sizes, int n_in,
                              void* d_out, int out_size, void* d_ws, size_t ws_size,
                              hipStream_t stream) {
    const float* src = (const float*)d_in[0];
    const float* tgt = (const float*)d_in[1];
    float* out = (float*)d_out;
    float* ws = (float*)d_ws;
    const size_t need = (size_t)CS_BLOCKS * MMD_D * sizeof(float) + 16;

    if (ws_size >= need) {
        mmd_onepass<<<CS_BLOCKS, CS_THREADS, 0, stream>>>(src, tgt, ws, out);
    } else {
        mmd_colsum_fb<<<CS_BLOCKS, CS_THREADS, 0, stream>>>(src, tgt, ws, out);
        mmd_finale_fb<<<64, 256, 0, stream>>>(ws, out);
    }
}

// Round 10
// 40.765 us; speedup vs baseline: 2.0942x; 2.0942x over previous
//
#include <hip/hip_runtime.h>

// MMD loss: mean(delta @ delta.T) == ||colsum(source - target)||^2 / N^2.
// O(N*D) streaming reduction (67 MB read).
// R8/R9 lessons: cg::grid.sync and acquire/release/threadfence protocols both
// collapse streaming (fence = L1-inv/L2-writeback storm), and the (,4)
// launch-bounds hint de-pipelined the loads (VGPR 32). This version fuses with
// ZERO cache fences: device-scope RELAXED atomics only (they execute at the
// coherent point -- R2 showed atomics write through to HBM), ordered by
// s_waitcnt vmcnt(0) (instruction completion, no cache op) + __syncthreads.
//   block0 entry: ctl0=ctl1=0, out=0 (atomic stores), vmcnt, flag=MAGIC
//   each block: R6 load engine -> LDS fold -> slice store as relaxed atomic
//     8B stores (write-through) -> vmcnt(0) -> barrier -> ticket RMW
//   last 64 tickets elected: spin ctl0==512 (relaxed+s_sleep), fold 4 cols
//     via relaxed atomic loads, 4 atomicAdd(out), then ctl1 RMW; the 64th
//     resets ctl -> 0 so the next replay starts clean.

#define MMD_N 8192
#define MMD_D 1024
#define CS_BLOCKS 512
#define CS_THREADS 512
#define TEAMS 2
#define ROWS_PER_TEAM 8   // CS_BLOCKS * TEAMS * ROWS_PER_TEAM == MMD_N
#define NFIN 64
#define MAGIC 0x7E11AD05u
#define INV_N2 1.4901161193847656e-8f  // 1 / 8192^2

#define A_LD(p)    __hip_atomic_load((p), __ATOMIC_RELAXED, __HIP_MEMORY_SCOPE_AGENT)
#define A_ST(p, v) __hip_atomic_store((p), (v), __ATOMIC_RELAXED, __HIP_MEMORY_SCOPE_AGENT)
#define A_ADD(p, v) __hip_atomic_fetch_add((p), (v), __ATOMIC_RELAXED, __HIP_MEMORY_SCOPE_AGENT)

union f2u { float f[2]; unsigned long long u; };

__global__ __launch_bounds__(CS_THREADS) void mmd_fused(
    const float* __restrict__ src, const float* __restrict__ tgt,
    float* __restrict__ ws, float* __restrict__ out) {
    const int tid  = threadIdx.x;
    const int team = tid >> 8;    // 0..1
    const int col4 = tid & 255;   // float4 column
    const int bid  = blockIdx.x;
    unsigned* ctl = reinterpret_cast<unsigned*>(ws + CS_BLOCKS * MMD_D);
    // ctl[0]=ticket, ctl[1]=finale-done, ctl[2]=init flag

    if (bid == 0 && tid == 0) {
        A_ST(&ctl[0], 0u);
        A_ST(&ctl[1], 0u);
        A_ST(reinterpret_cast<unsigned*>(out), 0u);  // coherent-point zero
        asm volatile("s_waitcnt vmcnt(0)" ::: "memory");
        A_ST(&ctl[2], MAGIC);
    }

    // ---- phase 1: R6-proven load engine (unchanged) ----
    const int row0 = bid * (TEAMS * ROWS_PER_TEAM) + team * ROWS_PER_TEAM;
    const float4* s4 = reinterpret_cast<const float4*>(src);
    const float4* t4 = reinterpret_cast<const float4*>(tgt);

    float4 s[ROWS_PER_TEAM], t[ROWS_PER_TEAM];
#pragma unroll
    for (int r = 0; r < ROWS_PER_TEAM; ++r)
        s[r] = s4[(row0 + r) * (MMD_D / 4) + col4];
#pragma unroll
    for (int r = 0; r < ROWS_PER_TEAM; ++r)
        t[r] = t4[(row0 + r) * (MMD_D / 4) + col4];

    float4 acc = make_float4(0.f, 0.f, 0.f, 0.f);
#pragma unroll
    for (int r = 0; r < ROWS_PER_TEAM; ++r) {
        acc.x += s[r].x - t[r].x;
        acc.y += s[r].y - t[r].y;
        acc.z += s[r].z - t[r].z;
        acc.w += s[r].w - t[r].w;
    }

    __shared__ float4 red[TEAMS][256];
    red[team][col4] = acc;
    __syncthreads();
    if (tid < 256) {
        float4 a = red[0][tid];
        float4 b = red[1][tid];
        f2u lo, hi;
        lo.f[0] = a.x + b.x; lo.f[1] = a.y + b.y;
        hi.f[0] = a.z + b.z; hi.f[1] = a.w + b.w;
        // slice store: relaxed atomic 8B stores = write-through, no fence
        unsigned long long* dst =
            reinterpret_cast<unsigned long long*>(ws) + (bid * 256 + tid) * 2;
        A_ST(&dst[0], lo.u);
        A_ST(&dst[1], hi.u);
    }
    // all waves: own stores complete at coherent point before ticket
    asm volatile("s_waitcnt vmcnt(0)" ::: "memory");
    __syncthreads();

    // ---- ticket ----
    __shared__ unsigned s_rank;
    if (tid == 0) {
        while (A_LD(&ctl[2]) != MAGIC) __builtin_amdgcn_s_sleep(1);
        s_rank = A_ADD(&ctl[0], 1u);
    }
    __syncthreads();
    const unsigned rank = s_rank;
    if (rank < CS_BLOCKS - NFIN) return;

    // ---- finale: elected 64 blocks ----
    if (tid == 0) {
        while (A_LD(&ctl[0]) < (unsigned)CS_BLOCKS) __builtin_amdgcn_s_sleep(2);
    }
    __syncthreads();

    const int r   = (int)rank - (CS_BLOCKS - NFIN);  // 0..63
    const int col = r * 4 + (tid >> 7);              // float4 column, 128 thr each
    const int sl0 = tid & 127;
    unsigned long long* w8 = reinterpret_cast<unsigned long long*>(ws);

    float4 a2 = make_float4(0.f, 0.f, 0.f, 0.f);
#pragma unroll
    for (int k = 0; k < CS_BLOCKS / 128; ++k) {      // 4 slices per thread
        const int idx = ((sl0 + 128 * k) * 256 + col) * 2;
        f2u lo, hi;
        lo.u = A_LD(&w8[idx]);      // coherent loads: no stale-cache risk
        hi.u = A_LD(&w8[idx + 1]);
        a2.x += lo.f[0]; a2.y += lo.f[1]; a2.z += hi.f[0]; a2.w += hi.f[1];
    }
    for (int off = 32; off > 0; off >>= 1) {
        a2.x += __shfl_down(a2.x, off, 64);
        a2.y += __shfl_down(a2.y, off, 64);
        a2.z += __shfl_down(a2.z, off, 64);
        a2.w += __shfl_down(a2.w, off, 64);
    }
    __shared__ float4 wred[8];
    if ((tid & 63) == 0) wred[tid >> 6] = a2;
    __syncthreads();
    if ((tid & 127) == 0) {
        float4 a = wred[tid >> 6];
        float4 b = wred[(tid >> 6) + 1];
        float4 tot;
        tot.x = a.x + b.x; tot.y = a.y + b.y;
        tot.z = a.z + b.z; tot.w = a.w + b.w;
        float sq = tot.x * tot.x + tot.y * tot.y + tot.z * tot.z + tot.w * tot.w;
        atomicAdd(out, sq * INV_N2);   // device-scope, coherent point
    }
    // all 4 out-adds of this block complete before the done-bump
    asm volatile("s_waitcnt vmcnt(0)" ::: "memory");
    __syncthreads();
    if (tid == 0) {
        unsigned d = A_ADD(&ctl[1], 1u);
        if (d == NFIN - 1) {          // 64th finale block: reset for next call
            A_ST(&ctl[2], 0u);
            A_ST(&ctl[0], 0u);
            A_ST(&ctl[1], 0u);
        }
    }
}

// ---------------- fallback: proven R6 2-kernel path ----------------
__global__ __launch_bounds__(CS_THREADS) void mmd_colsum_fb(
    const float* __restrict__ src, const float* __restrict__ tgt,
    float* __restrict__ ws, float* __restrict__ out) {
    const int tid  = threadIdx.x;
    const int team = tid >> 8;
    const int col4 = tid & 255;
    const int row0 = blockIdx.x * (TEAMS * ROWS_PER_TEAM) + team * ROWS_PER_TEAM;
    const float4* s4 = reinterpret_cast<const float4*>(src);
    const float4* t4 = reinterpret_cast<const float4*>(tgt);

    if (blockIdx.x == 0 && tid == 0) out[0] = 0.f;

    float4 s[ROWS_PER_TEAM], t[ROWS_PER_TEAM];
#pragma unroll
    for (int r = 0; r < ROWS_PER_TEAM; ++r)
        s[r] = s4[(row0 + r) * (MMD_D / 4) + col4];
#pragma unroll
    for (int r = 0; r < ROWS_PER_TEAM; ++r)
        t[r] = t4[(row0 + r) * (MMD_D / 4) + col4];

    float4 acc = make_float4(0.f, 0.f, 0.f, 0.f);
#pragma unroll
    for (int r = 0; r < ROWS_PER_TEAM; ++r) {
        acc.x += s[r].x - t[r].x;
        acc.y += s[r].y - t[r].y;
        acc.z += s[r].z - t[r].z;
        acc.w += s[r].w - t[r].w;
    }

    __shared__ float4 red[TEAMS][256];
    red[team][col4] = acc;
    __syncthreads();
    if (tid < 256) {
        float4 a = red[0][tid];
        float4 b = red[1][tid];
        float4 tot;
        tot.x = a.x + b.x; tot.y = a.y + b.y;
        tot.z = a.z + b.z; tot.w = a.w + b.w;
        reinterpret_cast<float4*>(ws)[blockIdx.x * 256 + tid] = tot;
    }
}

__global__ __launch_bounds__(256) void mmd_finale_fb(
    const float* __restrict__ ws, float* __restrict__ out) {
    const int tid  = threadIdx.x;
    const int j    = tid >> 6;
    const int lane = tid & 63;
    const int c    = blockIdx.x * 4 + j;
    const float4* w4 = reinterpret_cast<const float4*>(ws);

    float4 acc = make_float4(0.f, 0.f, 0.f, 0.f);
#pragma unroll
    for (int k = 0; k < CS_BLOCKS / 64; ++k) {
        float4 v = w4[(lane + 64 * k) * 256 + c];
        acc.x += v.x; acc.y += v.y; acc.z += v.z; acc.w += v.w;
    }
    for (int off = 32; off > 0; off >>= 1) {
        acc.x += __shfl_down(acc.x, off, 64);
        acc.y += __shfl_down(acc.y, off, 64);
        acc.z += __shfl_down(acc.z, off, 64);
        acc.w += __shfl_down(acc.w, off, 64);
    }
    if (lane == 0) {
        float sq = acc.x * acc.x + acc.y * acc.y + acc.z * acc.z + acc.w * acc.w;
        atomicAdd(out, sq * INV_N2);
    }
}

extern "C" void kernel_launch(void* const* d_in, const int* in_sizes, int n_in,
                              void* d_out, int out_size, void* d_ws, size_t ws_size,
                              hipStream_t stream) {
    const float* src = (const float*)d_in[0];
    const float* tgt = (const float*)d_in[1];
    float* out = (float*)d_out;
    float* ws = (float*)d_ws;
    const size_t need = (size_t)CS_BLOCKS * MMD_D * sizeof(float) + 16;

    if (ws_size >= need) {
        mmd_fused<<<CS_BLOCKS, CS_THREADS, 0, stream>>>(src, tgt, ws, out);
    } else {
        mmd_colsum_fb<<<CS_BLOCKS, CS_THREADS, 0, stream>>>(src, tgt, ws, out);
        mmd_finale_fb<<<64, 256, 0, stream>>>(ws, out);
    }
}

// Round 11
// 21.055 us; speedup vs baseline: 4.0546x; 1.9362x over previous
//
#include <hip/hip_runtime.h>

// MMD loss: mean(delta @ delta.T) == ||colsum(source - target)||^2 / N^2.
// O(N*D) streaming reduction (67 MB read).
// FINAL (revert to proven R6 structure): colsum streams at ~6.27 TB/s
// (99.7% of the measured float4-copy ceiling 6.29 TB/s); total = colsum
// 10.7us + finale ~2us + 2 graph nodes x ~4.2us overhead ~= 21us.
// Fusion post-mortem (R8/R9/R10): cg::grid.sync, acq/rel fence protocol,
// and fence-free relaxed-atomic ticket protocol ALL collapse streaming
// 5-10x on gfx950 -- single-kernel fusion is a dead end here; the 2-node
// structure is the optimum.
//  - 512 blocks x 512 threads, 2 teams x 8 rows, 16 float4 loads/thread
//  - colsum block 0 zeroes out[0] (no memset node)
//  - finale: column-partitioned over 64 blocks, shfl-reduce, 256 atomicAdds.

#define MMD_N 8192
#define MMD_D 1024
#define CS_BLOCKS 512
#define CS_THREADS 512
#define TEAMS 2
#define ROWS_PER_TEAM 8   // CS_BLOCKS * TEAMS * ROWS_PER_TEAM == MMD_N
#define INV_N2 1.4901161193847656e-8f  // 1 / 8192^2

__global__ __launch_bounds__(CS_THREADS) void mmd_colsum(
    const float* __restrict__ src, const float* __restrict__ tgt,
    float* __restrict__ ws, float* __restrict__ out) {
    const int tid  = threadIdx.x;
    const int team = tid >> 8;    // 0..1
    const int col4 = tid & 255;   // float4 column
    const int row0 = blockIdx.x * (TEAMS * ROWS_PER_TEAM) + team * ROWS_PER_TEAM;
    const float4* s4 = reinterpret_cast<const float4*>(src);
    const float4* t4 = reinterpret_cast<const float4*>(tgt);

    if (blockIdx.x == 0 && tid == 0) out[0] = 0.f;  // replaces memset node

    // Issue all 16 loads before any consumption: 8 from src, then 8 from tgt.
    float4 s[ROWS_PER_TEAM], t[ROWS_PER_TEAM];
#pragma unroll
    for (int r = 0; r < ROWS_PER_TEAM; ++r)
        s[r] = s4[(row0 + r) * (MMD_D / 4) + col4];
#pragma unroll
    for (int r = 0; r < ROWS_PER_TEAM; ++r)
        t[r] = t4[(row0 + r) * (MMD_D / 4) + col4];

    float4 acc = make_float4(0.f, 0.f, 0.f, 0.f);
#pragma unroll
    for (int r = 0; r < ROWS_PER_TEAM; ++r) {
        acc.x += s[r].x - t[r].x;
        acc.y += s[r].y - t[r].y;
        acc.z += s[r].z - t[r].z;
        acc.w += s[r].w - t[r].w;
    }

    // cross-team fold in LDS: 2 teams x 256 float4 = 8 KiB
    __shared__ float4 red[TEAMS][256];
    red[team][col4] = acc;
    __syncthreads();
    if (tid < 256) {
        float4 a = red[0][tid];
        float4 b = red[1][tid];
        float4 tot;
        tot.x = a.x + b.x;
        tot.y = a.y + b.y;
        tot.z = a.z + b.z;
        tot.w = a.w + b.w;
        // coalesced slice store: block bid owns ws[bid*1024 .. +1023]
        reinterpret_cast<float4*>(ws)[blockIdx.x * 256 + tid] = tot;
    }
}

// 64 blocks x 256 threads. Wave j of block b owns float4-column c = 4b + j;
// lanes split the 512 slices (8 each), shfl-reduce, square, one atomicAdd
// per wave (256 total).
__global__ __launch_bounds__(256) void mmd_finale(
    const float* __restrict__ ws, float* __restrict__ out) {
    const int tid  = threadIdx.x;
    const int j    = tid >> 6;   // wave id 0..3
    const int lane = tid & 63;
    const int c    = blockIdx.x * 4 + j;  // float4 column index 0..255
    const float4* w4 = reinterpret_cast<const float4*>(ws);

    float4 acc = make_float4(0.f, 0.f, 0.f, 0.f);
#pragma unroll
    for (int k = 0; k < CS_BLOCKS / 64; ++k) {  // 8 slices per lane
        float4 v = w4[(lane + 64 * k) * 256 + c];
        acc.x += v.x; acc.y += v.y; acc.z += v.z; acc.w += v.w;
    }
    for (int off = 32; off > 0; off >>= 1) {
        acc.x += __shfl_down(acc.x, off, 64);
        acc.y += __shfl_down(acc.y, off, 64);
        acc.z += __shfl_down(acc.z, off, 64);
        acc.w += __shfl_down(acc.w, off, 64);
    }
    if (lane == 0) {
        float sq = acc.x * acc.x + acc.y * acc.y + acc.z * acc.z + acc.w * acc.w;
        atomicAdd(out, sq * INV_N2);
    }
}

extern "C" void kernel_launch(void* const* d_in, const int* in_sizes, int n_in,
                              void* d_out, int out_size, void* d_ws, size_t ws_size,
                              hipStream_t stream) {
    const float* src = (const float*)d_in[0];
    const float* tgt = (const float*)d_in[1];
    float* out = (float*)d_out;
    float* ws = (float*)d_ws;  // needs CS_BLOCKS * MMD_D floats = 2 MiB

    mmd_colsum<<<CS_BLOCKS, CS_THREADS, 0, stream>>>(src, tgt, ws, out);
    mmd_finale<<<64, 256, 0, stream>>>(ws, out);
}